// Round 4
// baseline (311.172 us; speedup 1.0000x reference)
//
#include <hip/hip_runtime.h>
#include <hip/hip_bf16.h>
#include <stdint.h>

// MozafariMNIST2018 forward. B=4096, T=15, HW=784, F1=500, F3=10.
// Output layout (float32, concatenated):
//   spk1 [4096*15*500] @ 0
//   thr1 [4096*15*500] @ 30720000
//   pot3 [4096*15*10]  @ 61440000
//   cls  [4096]        @ 62054400
//
// conv1: single-f16 MFMA (weights pre-rounded to f16 by k_prep into a
// global_load_lds-ready swizzled layout). Any pot1 near the fire threshold
// implies only ~33 active pixels => f16 error <= ~0.011, so elements with
// |p - THR| < 0.0625 are recomputed exactly in fp32 (rare fixup) making
// spikes exact. conv3 is FUSED into conv1's epilogue (per-wave partials ->
// LDS reduce -> atomicAdd, exactly 2 contributors per output => bitwise
// deterministic). Winner-take-all reads pot3[b,14,:].

typedef _Float16 f16x8 __attribute__((ext_vector_type(8)));
typedef float    f32x4 __attribute__((ext_vector_type(4)));

typedef __attribute__((address_space(3))) char        lds_char_t;
typedef const __attribute__((address_space(1))) char  gbl_char_t;

#define GLL16(gsrc, ldst) \
  __builtin_amdgcn_global_load_lds((gbl_char_t*)(gsrc), (lds_char_t*)(ldst), 16, 0, 0)

#define CONV1_T   26.3424f
#define FIX_DELTA 0.0625f
#define KDIM 784
#define F1   500

// ------------------------------------------------------------------
// k_prep: round w1 [500x784] fp32 -> f16, in conv1's LDS tile byte order.
// Tile (nb*25+ks) is 16384 B; chunk c (16B): nl=c>>2, slot=c&3,
// k-chunk j = slot ^ ((nl>>1)&3) (XOR bank swizzle), ng = nb*256+nl.
// ------------------------------------------------------------------
__global__ __launch_bounds__(256)
void k_prep(const float* __restrict__ w1, float* __restrict__ scratch)
{
    const int c = blockIdx.x * 256 + threadIdx.x;   // < 51200
    const int tile  = c >> 10;
    const int chunk = c & 1023;
    const int nb   = tile / 25;
    const int ks   = tile % 25;
    const int nl   = chunk >> 2;
    const int slot = chunk & 3;
    const int j    = slot ^ ((nl >> 1) & 3);
    const int k0   = ks * 32 + j * 8;
    const int ng   = nb * 256 + nl;

    f16x8 v;
    #pragma unroll
    for (int e = 0; e < 8; ++e) {
        const int kk = k0 + e;
        v[e] = (ng < F1 && kk < KDIM) ? (_Float16)w1[ng * KDIM + kk] : (_Float16)0.f;
    }
    *(f16x8*)((char*)scratch + (size_t)c * 16) = v;
}

__global__ __launch_bounds__(256)
void k_zero(float* __restrict__ p, int n)
{
    const int i = blockIdx.x * 256 + threadIdx.x;
    if (i < n) p[i] = 0.f;
}

// exact fp32 recompute for near-threshold elements (rare)
__device__ __attribute__((noinline))
float fix_dot(const float* __restrict__ a, const float* __restrict__ w)
{
    float s0 = 0.f, s1 = 0.f, s2 = 0.f, s3 = 0.f;
    for (int k = 0; k < KDIM; k += 4) {
        s0 = fmaf(a[k],     w[k],     s0);
        s1 = fmaf(a[k + 1], w[k + 1], s1);
        s2 = fmaf(a[k + 2], w[k + 2], s2);
        s3 = fmaf(a[k + 3], w[k + 3], s3);
    }
    return (s0 + s1) + (s2 + s3);
}

// ------------------------------------------------------------------
// k_conv1: pot1 = A[61440x784] * w1^T (f16), fire, fused conv3 partials.
// Tile BM=128, BN=256 (nb half), BK=32. 512 thr = 8 waves (2M x 4N),
// per-wave 64x64 output. Double-buffered LDS, 2-phase prefetch.
// ------------------------------------------------------------------
template<bool FUSED>
__global__ __launch_bounds__(512, 4)
void k_conv1(const float* __restrict__ inp, const float* __restrict__ bsplit,
             const float* __restrict__ w1, const float* __restrict__ w3,
             float* __restrict__ spk1, float* __restrict__ thr1,
             float* __restrict__ pot3)
{
    __shared__ char smem[49152];
    _Float16* sA = (_Float16*)smem;              // 2 x 8192 B
    _Float16* sB = (_Float16*)(smem + 16384);    // 2 x 16384 B

    const int tid  = threadIdx.x;
    const int lane = tid & 63;
    const int wid  = tid >> 6;     // 0..7
    const int wm   = wid >> 2;     // 0..1 (M)
    const int wn   = wid & 3;      // 0..3 (N)
    const int lr   = lane & 15;
    const int kg   = lane >> 4;

    // XCD pairing: bx and bx^8 share the same A tile on the same XCD.
    const int bx   = blockIdx.x;                    // 0..959
    const int nb   = (bx >> 3) & 1;
    const int mblk = ((bx >> 4) << 3) | (bx & 7);   // 0..479
    const long long rowBase = (long long)mblk * 128;

    // A staging role
    const int sm  = tid >> 2;      // 0..127
    const int sk8 = tid & 3;
    const int aWr = sm * 32 + (sk8 ^ ((sm >> 1) & 3)) * 8;
    const float* gA = inp + (rowBase + sm) * KDIM + sk8 * 8;

    // B: global_load_lds source (lane's 16B baked in); 2 x 1KB per wave
    const char* gBsrc = (const char*)bsplit + (size_t)(nb * 25) * 16384
                      + (size_t)wid * 2048 + (size_t)lane * 16;

    f32x4 acc[4][4];
    #pragma unroll
    for (int i = 0; i < 4; ++i)
        #pragma unroll
        for (int j = 0; j < 4; ++j) acc[i][j] = {0.f, 0.f, 0.f, 0.f};

    int aOff[4], bOff[4];
    #pragma unroll
    for (int fm = 0; fm < 4; ++fm) {
        const int r = wm * 64 + fm * 16 + lr;
        aOff[fm] = r * 32 + (kg ^ ((r >> 1) & 3)) * 8;
    }
    #pragma unroll
    for (int fn = 0; fn < 4; ++fn) {
        const int n = wn * 64 + fn * 16 + lr;
        bOff[fn] = n * 32 + (kg ^ ((n >> 1) & 3)) * 8;
    }

    // ---- prologue: stage ks=0 into buffer 0
    {
        const f32x4 x0 = *(const f32x4*)(gA);
        const f32x4 x1 = *(const f32x4*)(gA + 4);
        #pragma unroll
        for (int i = 0; i < 2; ++i)
            GLL16(gBsrc + i * 1024,
                  (lds_char_t*)smem + 16384 + (size_t)wid * 2048 + i * 1024);
        f16x8 v;
        #pragma unroll
        for (int e = 0; e < 4; ++e) { v[e] = (_Float16)x0[e]; v[e + 4] = (_Float16)x1[e]; }
        *(f16x8*)&sA[aWr] = v;
    }
    __syncthreads();

    for (int ks = 0; ks < 25; ++ks) {
        const int  cur = ks & 1;
        const bool pf  = (ks + 1 < 25);

        // ---- issue prefetch for tile ks+1 into buffer cur^1
        f32x4 x0 = {0.f, 0.f, 0.f, 0.f}, x1 = {0.f, 0.f, 0.f, 0.f};
        bool av = false;
        if (pf) {
            const int k0 = (ks + 1) * 32 + sk8 * 8;
            av = (k0 + 8 <= KDIM);
            if (av) {
                x0 = *(const f32x4*)(gA + (ks + 1) * 32);
                x1 = *(const f32x4*)(gA + (ks + 1) * 32 + 4);
            }
            const char*  src = gBsrc + (size_t)(ks + 1) * 16384;
            lds_char_t*  dst = (lds_char_t*)smem + 16384 + (size_t)(cur ^ 1) * 16384
                             + (size_t)wid * 2048;
            #pragma unroll
            for (int i = 0; i < 2; ++i)
                GLL16(src + i * 1024, dst + i * 1024);
        }

        // ---- compute tile ks from buffer cur
        const _Float16* sAc = sA + cur * 4096;
        const _Float16* sBc = sB + cur * 8192;
        const f16x8 a0 = *(const f16x8*)&sAc[aOff[0]];
        const f16x8 a1 = *(const f16x8*)&sAc[aOff[1]];
        const f16x8 a2 = *(const f16x8*)&sAc[aOff[2]];
        const f16x8 a3 = *(const f16x8*)&sAc[aOff[3]];
        #pragma unroll
        for (int fn = 0; fn < 4; ++fn) {
            const f16x8 bh = *(const f16x8*)&sBc[bOff[fn]];
            acc[0][fn] = __builtin_amdgcn_mfma_f32_16x16x32_f16(a0, bh, acc[0][fn], 0, 0, 0);
            acc[1][fn] = __builtin_amdgcn_mfma_f32_16x16x32_f16(a1, bh, acc[1][fn], 0, 0, 0);
            acc[2][fn] = __builtin_amdgcn_mfma_f32_16x16x32_f16(a2, bh, acc[2][fn], 0, 0, 0);
            acc[3][fn] = __builtin_amdgcn_mfma_f32_16x16x32_f16(a3, bh, acc[3][fn], 0, 0, 0);
        }

        // ---- finish A prefetch: cvt + LDS write into buffer cur^1
        if (pf) {
            f16x8 v;
            #pragma unroll
            for (int e = 0; e < 4; ++e) {
                v[e]     = av ? (_Float16)x0[e] : (_Float16)0.f;
                v[e + 4] = av ? (_Float16)x1[e] : (_Float16)0.f;
            }
            *(f16x8*)&sA[(cur ^ 1) * 4096 + aWr] = v;
        }
        __syncthreads();
    }

    // ---- epilogue: fixup + fire + write. C/D: col=lane&15, row=(lane>>4)*4+r
    #pragma unroll
    for (int fm = 0; fm < 4; ++fm) {
        #pragma unroll
        for (int fn = 0; fn < 4; ++fn) {
            const int ng = nb * 256 + wn * 64 + fn * 16 + lr;
            if (ng < F1) {
                #pragma unroll
                for (int r = 0; r < 4; ++r) {
                    const long long m = rowBase + wm * 64 + fm * 16 + kg * 4 + r;
                    float p = acc[fm][fn][r];
                    if (__builtin_expect(fabsf(p - CONV1_T) < FIX_DELTA, 0)) {
                        p = fix_dot(inp + m * KDIM, w1 + (size_t)ng * KDIM);
                        acc[fm][fn][r] = p;
                    }
                    const bool fire = (p >= CONV1_T);
                    thr1[m * F1 + ng] = fire ? p : 0.f;
                    spk1[m * F1 + ng] = fire ? 1.f : 0.f;
                }
            }
        }
    }

    if constexpr (FUSED) {
        // ---- fused conv3: pot3[m,g] += sum over this block's 256 f's
        float* sw3   = (float*)smem;             // 20000 B
        float* spart = (float*)(smem + 20480);   // 4*128*10*4 = 20480 B
        __syncthreads();                          // main-loop LDS reuse safe
        for (int i = tid; i < 5000; i += 512) sw3[i] = w3[i];
        __syncthreads();

        #pragma unroll
        for (int fm = 0; fm < 4; ++fm) {
            #pragma unroll
            for (int r = 0; r < 4; ++r) {
                const int mr = wm * 64 + fm * 16 + kg * 4 + r;
                float pg[10];
                #pragma unroll
                for (int g = 0; g < 10; ++g) pg[g] = 0.f;
                #pragma unroll
                for (int fn = 0; fn < 4; ++fn) {
                    const int ng = nb * 256 + wn * 64 + fn * 16 + lr;
                    const bool s = (ng < F1) && (acc[fm][fn][r] >= CONV1_T);
                    if (s) {
                        #pragma unroll
                        for (int g = 0; g < 10; ++g) pg[g] += sw3[g * F1 + ng];
                    }
                }
                // reduce across the 16 lr lanes
                #pragma unroll
                for (int off = 1; off < 16; off <<= 1) {
                    #pragma unroll
                    for (int g = 0; g < 10; ++g) pg[g] += __shfl_xor(pg[g], off);
                }
                if (lr == 0) {
                    #pragma unroll
                    for (int g = 0; g < 10; ++g)
                        spart[(wn * 128 + mr) * 10 + g] = pg[g];
                }
            }
        }
        __syncthreads();
        for (int idx = tid; idx < 1280; idx += 512) {
            const int row = idx / 10, g = idx % 10;
            const float s = spart[idx] + spart[1280 + idx]
                          + spart[2560 + idx] + spart[3840 + idx];
            atomicAdd(&pot3[(rowBase + row) * 10 + g], s);
        }
    }
}

// ------------------------------------------------------------------
// k_conv3 (fallback when d_ws too small for scratch+atomics path)
// ------------------------------------------------------------------
__global__ __launch_bounds__(512)
void k_conv3(const float* __restrict__ spk1, const float* __restrict__ w3,
             float* __restrict__ pot3)
{
    __shared__ float sw[5000];
    const int tid = threadIdx.x;
    for (int i = tid; i < 5000; i += 512) sw[i] = w3[i];
    __syncthreads();

    const int lane = tid & 63;
    const int wr   = tid >> 6;
    const long long row = (long long)blockIdx.x * 8 + wr;
    const float* sr = spk1 + row * F1;

    float ps[10];
    #pragma unroll
    for (int g = 0; g < 10; ++g) ps[g] = 0.f;

    const int f0 = lane * 8;
    if (f0 < F1) {
        const f32x4 v0 = *(const f32x4*)(sr + f0);
        f32x4 v1 = {0.f, 0.f, 0.f, 0.f};
        if (f0 + 4 < F1) v1 = *(const f32x4*)(sr + f0 + 4);
        const float v[8] = {v0[0], v0[1], v0[2], v0[3], v1[0], v1[1], v1[2], v1[3]};
        #pragma unroll
        for (int e = 0; e < 8; ++e) {
            const int f = f0 + e;
            if (f < F1) {
                const float s = v[e];
                #pragma unroll
                for (int g = 0; g < 10; ++g) ps[g] += s * sw[g * F1 + f];
            }
        }
    }
    #pragma unroll
    for (int g = 0; g < 10; ++g) {
        float t = ps[g];
        #pragma unroll
        for (int off = 32; off; off >>= 1) t += __shfl_xor(t, off);
        if (lane == 0) pot3[row * 10 + g] = t;
    }
}

// ------------------------------------------------------------------
// k_winner: winner-take-all per batch, faithful to reference algebra.
// ------------------------------------------------------------------
__global__ __launch_bounds__(256)
void k_winner(const float* __restrict__ pot3, float* __restrict__ outCls, int nB)
{
    const int b = blockIdx.x * 256 + threadIdx.x;
    if (b >= nB) return;
    const float* p = pot3 + (long long)b * 150 + 140;   // t = 14 row

    float pv[10], s[10];
    float mv = 0.f;
    #pragma unroll
    for (int g = 0; g < 10; ++g) {
        const float v = p[g];
        pv[g] = v;
        s[g]  = (v > 0.f) ? 1.f : ((v < 0.f) ? -1.f : 0.f);
        mv = fmaxf(mv, s[g] * v);
    }
    const float vbig = mv * 15.f;
    float bm = -INFINITY; int bi = 0;
    #pragma unroll
    for (int g = 0; g < 10; ++g) {
        const float tot = s[g] * pv[g] + s[g] * vbig;
        if (tot > bm) { bm = tot; bi = g; }
    }
    outCls[b] = (bm != 0.f) ? (float)bi : -1.f;
}

// ------------------------------------------------------------------
extern "C" void kernel_launch(void* const* d_in, const int* in_sizes, int n_in,
                              void* d_out, int out_size, void* d_ws, size_t ws_size,
                              hipStream_t stream)
{
    const float* inp = (const float*)d_in[0];
    const float* w1  = (const float*)d_in[1];
    const float* w3  = (const float*)d_in[2];

    float* out  = (float*)d_out;
    float* spk1 = out;
    float* thr1 = out + 30720000LL;
    float* pot3 = out + 61440000LL;
    float* cls  = out + 62054400LL;

    if (ws_size >= 819200) {
        // fused path: scratch in d_ws, pot3 accumulated by atomics in conv1
        float* scratch = (float*)d_ws;
        k_prep        <<<200,  256, 0, stream>>>(w1, scratch);
        k_zero        <<<2400, 256, 0, stream>>>(pot3, 614400);
        k_conv1<true> <<<960,  512, 0, stream>>>(inp, scratch, w1, w3, spk1, thr1, pot3);
        k_winner      <<<16,   256, 0, stream>>>(pot3, cls, 4096);
    } else {
        // fallback: scratch borrows pot3 region (read-only in conv1),
        // conv3 overwrites it afterwards
        float* scratch = pot3;
        k_prep        <<<200,  256, 0, stream>>>(w1, scratch);
        k_conv1<false><<<960,  512, 0, stream>>>(inp, scratch, w1, w3, spk1, thr1, nullptr);
        k_conv3       <<<7680, 512, 0, stream>>>(spk1, w3, pot3);
        k_winner      <<<16,   256, 0, stream>>>(pot3, cls, 4096);
    }
}